// Round 11
// baseline (95.261 us; speedup 1.0000x reference)
//
#include <hip/hip_runtime.h>
#include <hip/hip_bf16.h>

// Problem constants (from reference): B=8, C=16, H=512, W=512, M=15, N=15
#define BC    128          // B*C
#define Hh    512
#define Ww    512
#define P16   16           // M+1
#define Q16   16           // N+1
#define HTILE 64           // h rows per block -> grid 8*128 = 1024 = 4 blocks/CU
#define NHT   (Hh / HTILE) // 8 h-tiles
#define PQ    (P16 * Q16)  // 256 floats per basis row
#define BROW  ((size_t)Ww * PQ)   // 131072 floats between h-rows of basis

// ---------------------------------------------------------------------------
// Single fused kernel. Factorization without any precompute pass:
//   basis[n,p,q] = Bu[h,p]*Bv[w,q]  (n = h*W + w, exact fp32 product)
//   Bu_raw[h,p] := basis[h*W, p, 0] = Bu[h,p]*Bv[0,0]
//   Bv_raw[w,q] := basis[w, 0, q]   = Bu[0,0]*Bv[w,q]
//   => out[h,w] = (1/basis[0]) * sum_p Bu_raw[h,p] * sum_q K[p,q]*Bv_raw[w,q]
// Thread t owns w-pair 2t,2t+1 and all 64 h rows of its tile.
//   Phase A: T[p] = sum_q K[p,q]*Bv_raw[.,q]   (16 x float2 = 32 VGPRs)
//            then T *= 1/basis[0]              (folds both divisions)
//   Phase B: per h-pair, lane-pair __shfl_xor repack -> regular b128 stores
//            (R9/R10 A/B: regular b128 = 35.9us, NT b128 = 39.5us).
//   K and Bu_raw addresses are block-uniform -> scalar loads; zero LDS,
//   zero barriers, spill-proof live set (~60 VGPR).
// ---------------------------------------------------------------------------
__global__ __launch_bounds__(256, 4)
void bezier_fused(const float* __restrict__ K,
                  const float* __restrict__ basis,
                  float* __restrict__ out) {
    const int t     = threadIdx.x;       // 0..255
    const int htile = blockIdx.x;        // 0..7
    const int bc    = blockIdx.y;        // 0..127

    const float* __restrict__ Kp = K + (size_t)bc * PQ;   // uniform

    // ---- Phase A: T[p] = sum_q K[p,q] * Bv_raw[w,q] for w = 2t, 2t+1 ----
    // Bv_raw row w = basis + w*256 floats (16 floats, 64 B, float4-aligned)
    const float4* bv0 = (const float4*)(basis + (size_t)(2 * t) * PQ);
    const float4* bv1 = (const float4*)(basis + (size_t)(2 * t + 1) * PQ);

    float2 T[P16];
    #pragma unroll
    for (int p = 0; p < P16; ++p) T[p] = make_float2(0.f, 0.f);

    #pragma unroll
    for (int qb = 0; qb < 2; ++qb) {               // q in blocks of 8
        float4 r00 = bv0[qb * 2 + 0], r01 = bv0[qb * 2 + 1];   // row 2t
        float4 r10 = bv1[qb * 2 + 0], r11 = bv1[qb * 2 + 1];   // row 2t+1
        #pragma unroll
        for (int p = 0; p < P16; ++p) {
            const float* kq = Kp + p * Q16 + qb * 8;   // uniform -> scalar loads
            float2 s = T[p];
            s.x = fmaf(kq[0], r00.x, s.x);  s.y = fmaf(kq[0], r10.x, s.y);
            s.x = fmaf(kq[1], r00.y, s.x);  s.y = fmaf(kq[1], r10.y, s.y);
            s.x = fmaf(kq[2], r00.z, s.x);  s.y = fmaf(kq[2], r10.z, s.y);
            s.x = fmaf(kq[3], r00.w, s.x);  s.y = fmaf(kq[3], r10.w, s.y);
            s.x = fmaf(kq[4], r01.x, s.x);  s.y = fmaf(kq[4], r11.x, s.y);
            s.x = fmaf(kq[5], r01.y, s.x);  s.y = fmaf(kq[5], r11.y, s.y);
            s.x = fmaf(kq[6], r01.z, s.x);  s.y = fmaf(kq[6], r11.z, s.y);
            s.x = fmaf(kq[7], r01.w, s.x);  s.y = fmaf(kq[7], r11.w, s.y);
            T[p] = s;
        }
    }

    // Fold both separability divisions into one scale: 1/basis[0,0,0].
    const float scale = 1.0f / basis[0];           // uniform scalar load
    #pragma unroll
    for (int p = 0; p < P16; ++p) { T[p].x *= scale; T[p].y *= scale; }

    // ---- Phase B: 64 rows in pairs; regular b128 stores via lane-pair repack
    // Bu_raw[hh,p] = basis[hh*BROW + p*16]  (block-uniform -> scalar loads)
    const size_t hbase = (size_t)htile * HTILE;
    const float* __restrict__ bu = basis + hbase * BROW;
    float* __restrict__ outbase =
        out + ((size_t)bc * Hh + hbase) * Ww + 2 * t;

    const bool odd = (t & 1);
    const int wofs = odd ? -2 : 0;

    #pragma unroll 4
    for (int h = 0; h < HTILE; h += 2) {
        const float* br0 = bu + (size_t)h * BROW;
        const float* br1 = br0 + BROW;
        float ax = 0.f, ay = 0.f, bx = 0.f, by = 0.f;
        #pragma unroll
        for (int p = 0; p < P16; ++p) {
            float c0 = br0[p * Q16], c1 = br1[p * Q16];   // uniform scalar loads
            ax = fmaf(c0, T[p].x, ax);
            ay = fmaf(c0, T[p].y, ay);
            bx = fmaf(c1, T[p].x, bx);
            by = fmaf(c1, T[p].y, by);
        }
        // lane-pair exchange: even lane emits row h (w=2t..2t+3),
        // odd lane emits row h+1 (w=2t-2..2t+1)
        float sx = __shfl_xor(ax, 1);
        float sy = __shfl_xor(ay, 1);
        float ux = __shfl_xor(bx, 1);
        float uy = __shfl_xor(by, 1);
        float4 v = odd ? make_float4(ux, uy, bx, by)
                       : make_float4(ax, ay, sx, sy);
        const int hrow = h + (odd ? 1 : 0);
        *(float4*)(outbase + (size_t)hrow * Ww + wofs) = v;  // global_store_dwordx4
    }
}

extern "C" void kernel_launch(void* const* d_in, const int* in_sizes, int n_in,
                              void* d_out, int out_size, void* d_ws, size_t ws_size,
                              hipStream_t stream) {
    const float* K     = (const float*)d_in[0];   // [128, 16, 16]
    const float* basis = (const float*)d_in[1];   // [262144, 16, 16]
    float* out = (float*)d_out;                   // [128, 512, 512]

    dim3 grid(NHT, BC);                           // 1024 blocks = 4/CU, one round
    bezier_fused<<<grid, 256, 0, stream>>>(K, basis, out);
}

// Round 12
// 35.923 us; speedup vs baseline: 2.6518x; 2.6518x over previous
//
#include <hip/hip_runtime.h>
#include <hip/hip_bf16.h>

// Problem constants (from reference): B=8, C=16, H=512, W=512, M=15, N=15
#define BC    128          // B*C
#define Hh    512
#define Ww    512
#define P16   16           // M+1
#define Q16   16           // N+1
#define HTILE 64           // h rows per eval block -> grid 8*128 = 1024 = 4 blocks/CU
#define NHT   (Hh / HTILE) // 8 h-tiles

// ---------------------------------------------------------------------------
// Kernel 1: extract separable factors by DIVISION (basis entries are exact
// fp32 products Bu[h,p]*Bv[w,q]; R10 validated absmax unchanged):
//   Bu00    = sum_q basis[0,0,q]            (partition of unity: = Bu[0,0])
//   Bv[w,q] = basis[w, 0, q]   / Bu00
//   Bu[h,p] = basis[h*W, p, 0] / Bv[0,0],  Bv[0,0] = basis[0]/Bu00
// One load + one mul per output element; 16384 threads. Writes COMPACT
// 32 KiB tables (R11 lesson: eval reading factors straight from basis is a
// 2.7x regression — the compact staging tables are load-bearing).
// ---------------------------------------------------------------------------
__global__ __launch_bounds__(256)
void extract_factors(const float* __restrict__ basis,
                     float* __restrict__ Bu,
                     float* __restrict__ Bv) {
    float bu00 = 0.f;
    #pragma unroll
    for (int q = 0; q < Q16; ++q) bu00 += basis[q];     // basis[0,0,q], uniform
    const float rinv  = 1.0f / bu00;                    // 1/Bu[0,0]
    const float rinv2 = bu00 / basis[0];                // 1/Bv[0,0]

    int tid = blockIdx.x * 256 + threadIdx.x;           // 0..16383
    if (tid < Hh * P16) {
        int h = tid >> 4, p = tid & 15;
        float v = basis[(size_t)h * Ww * (P16 * Q16) + p * Q16];  // basis[h*W, p, 0]
        Bu[tid] = v * rinv2;
    } else {
        int t2 = tid - Hh * P16;                        // (w,q) flat
        float v = basis[(size_t)(t2 >> 4) * (P16 * Q16) + (t2 & 15)];  // basis[w, 0, q]
        Bv[t2] = v * rinv;
    }
}

// ---------------------------------------------------------------------------
// Kernel 2 — identical to R9's measured-best eval (35.9 us config):
//   register-resident, zero LDS, zero barriers; thread t owns w-pair 2t,2t+1
//   and all 64 h rows. Phase A: T[p] = sum_q K[p,q]*Bv[w,q] (32 VGPRs).
//   Phase B: h in pairs, lane-pair __shfl_xor repack -> REGULAR b128 stores
//   (A/B history: b64 reg 38.8 | b64 NT 39.9 | b128 reg 35.9 | b128 NT 39.5).
// ---------------------------------------------------------------------------
__global__ __launch_bounds__(256, 4)
void bezier_eval(const float* __restrict__ K,
                 const float* __restrict__ Bu,
                 const float* __restrict__ Bv,
                 float* __restrict__ out) {
    const int t     = threadIdx.x;       // 0..255
    const int htile = blockIdx.x;        // 0..7
    const int bc    = blockIdx.y;        // 0..127

    const float* __restrict__ Kp = K + (size_t)bc * (P16 * Q16);  // uniform

    // ---- Phase A: build T[p] = (T[p][2t], T[p][2t+1]) ----
    float2 T[P16];
    #pragma unroll
    for (int p = 0; p < P16; ++p) T[p] = make_float2(0.f, 0.f);

    const float4* bvv = (const float4*)(Bv + (size_t)(2 * t) * Q16);

    #pragma unroll
    for (int qb = 0; qb < 2; ++qb) {               // q in blocks of 8
        float4 r00 = bvv[qb * 2 + 0], r01 = bvv[qb * 2 + 1];         // row 2t
        float4 r10 = bvv[4 + qb * 2 + 0], r11 = bvv[4 + qb * 2 + 1]; // row 2t+1
        #pragma unroll
        for (int p = 0; p < P16; ++p) {
            const float* kq = Kp + p * Q16 + qb * 8;   // uniform -> scalar loads
            float2 s = T[p];
            s.x = fmaf(kq[0], r00.x, s.x);  s.y = fmaf(kq[0], r10.x, s.y);
            s.x = fmaf(kq[1], r00.y, s.x);  s.y = fmaf(kq[1], r10.y, s.y);
            s.x = fmaf(kq[2], r00.z, s.x);  s.y = fmaf(kq[2], r10.z, s.y);
            s.x = fmaf(kq[3], r00.w, s.x);  s.y = fmaf(kq[3], r10.w, s.y);
            s.x = fmaf(kq[4], r01.x, s.x);  s.y = fmaf(kq[4], r11.x, s.y);
            s.x = fmaf(kq[5], r01.y, s.x);  s.y = fmaf(kq[5], r11.y, s.y);
            s.x = fmaf(kq[6], r01.z, s.x);  s.y = fmaf(kq[6], r11.z, s.y);
            s.x = fmaf(kq[7], r01.w, s.x);  s.y = fmaf(kq[7], r11.w, s.y);
            T[p] = s;
        }
    }

    // ---- Phase B: 64 rows in pairs; regular b128 stores via lane-pair repack
    const float* __restrict__ bu = Bu + (size_t)htile * (HTILE * P16);
    float* __restrict__ outbase =
        out + ((size_t)bc * Hh + (size_t)htile * HTILE) * Ww + 2 * t;

    const bool odd = (t & 1);
    const int wofs = odd ? -2 : 0;

    #pragma unroll 4
    for (int h = 0; h < HTILE; h += 2) {
        const float* br0 = bu + h * P16;           // uniform -> scalar loads (4 KB table)
        const float* br1 = br0 + P16;
        float ax = 0.f, ay = 0.f, bx = 0.f, by = 0.f;
        #pragma unroll
        for (int p = 0; p < P16; ++p) {
            float c0 = br0[p], c1 = br1[p];
            ax = fmaf(c0, T[p].x, ax);
            ay = fmaf(c0, T[p].y, ay);
            bx = fmaf(c1, T[p].x, bx);
            by = fmaf(c1, T[p].y, by);
        }
        // lane-pair exchange: even lane emits row h (w=2t..2t+3),
        // odd lane emits row h+1 (w=2t-2..2t+1)
        float sx = __shfl_xor(ax, 1);
        float sy = __shfl_xor(ay, 1);
        float ux = __shfl_xor(bx, 1);
        float uy = __shfl_xor(by, 1);
        float4 v = odd ? make_float4(ux, uy, bx, by)
                       : make_float4(ax, ay, sx, sy);
        const int hrow = h + (odd ? 1 : 0);
        *(float4*)(outbase + (size_t)hrow * Ww + wofs) = v;  // global_store_dwordx4
    }
}

extern "C" void kernel_launch(void* const* d_in, const int* in_sizes, int n_in,
                              void* d_out, int out_size, void* d_ws, size_t ws_size,
                              hipStream_t stream) {
    const float* K     = (const float*)d_in[0];   // [128, 16, 16]
    const float* basis = (const float*)d_in[1];   // [262144, 16, 16]
    float* out = (float*)d_out;                   // [128, 512, 512]

    float* Bu = (float*)d_ws;                     // [512][16]  (32 KiB)
    float* Bv = Bu + Hh * P16;                    // [512][16]  (32 KiB)

    extract_factors<<<64, 256, 0, stream>>>(basis, Bu, Bv);

    dim3 grid(NHT, BC);                           // 1024 blocks = 4/CU, one round
    bezier_eval<<<grid, 256, 0, stream>>>(K, Bu, Bv, out);
}